// Round 2
// baseline (1420.293 us; speedup 1.0000x reference)
//
#include <hip/hip_runtime.h>

typedef unsigned short u16;
typedef unsigned int u32;
typedef __attribute__((ext_vector_type(8))) short bf16x8;   // 8 bf16 (4 VGPRs)
typedef __attribute__((ext_vector_type(4))) float f32x4;    // 4 fp32 acc

#define NN 50000    // nodes
#define NE 800000   // edges
#define F0 1433     // in feats
#define KP 1440     // padded K (45 * 32)
#define MP 50048    // padded M (391 * 128)
#define D1 256
#define D2 32

__device__ __forceinline__ float bf2f(u16 h) { return __uint_as_float(((u32)h) << 16); }
__device__ __forceinline__ u16 f2bf(float f) {
  u32 u = __float_as_uint(f);
  u32 r = (u + 0x7FFFu + ((u >> 16) & 1u)) >> 16;  // RNE
  return (u16)r;
}

// async global->LDS, 16B per lane; LDS dest is wave-uniform base + lane*16
__device__ __forceinline__ void gl16(const void* g, void* l) {
  __builtin_amdgcn_global_load_lds((const __attribute__((address_space(1))) u32*)g,
                                   (__attribute__((address_space(3))) u32*)l, 16, 0, 0);
}

// ---------------- degree / norm ----------------
__global__ __launch_bounds__(256) void k_deg(const int* __restrict__ ei,
                                             float* __restrict__ dout,
                                             float* __restrict__ din) {
  const int e = blockIdx.x * 256 + threadIdx.x;
  if (e < NE) {
    atomicAdd(&dout[ei[e]], 1.0f);
    atomicAdd(&din[ei[NE + e]], 1.0f);
  }
}

__global__ __launch_bounds__(256) void k_rsqrt(float* __restrict__ a, float* __restrict__ b) {
  const int i = blockIdx.x * 256 + threadIdx.x;
  if (i < NN) {
    a[i] = rsqrtf(fmaxf(a[i], 1.0f));
    b[i] = rsqrtf(fmaxf(b[i], 1.0f));
  }
}

// ---------------- pad+convert features fp32 [NN][F0] -> bf16 [MP][KP] ----------------
__global__ __launch_bounds__(256) void k_padA(const float* __restrict__ F, u16* __restrict__ P) {
  const int t = blockIdx.x * 256 + threadIdx.x;  // 0..767, need 720
  if (t >= 720) return;
  const int i = blockIdx.y;
  const int k = t * 2;
  u32 v = 0;
  if (i < NN) {
    const size_t base = (size_t)i * F0;
    u32 lo = (k < F0) ? (u32)f2bf(F[base + k]) : 0u;
    u32 hi = (k + 1 < F0) ? (u32)f2bf(F[base + k + 1]) : 0u;
    v = lo | (hi << 16);
  }
  *(u32*)(P + (size_t)i * KP + k) = v;  // dst 4B-aligned (KP even)
}

// ---------------- weights: W1 fp32[F0][256] -> bf16 W1T[256][KP]; W2 fp32[256][32] -> bf16 W2T[32][256] ----------------
__global__ __launch_bounds__(256) void k_prepw(const float* __restrict__ W1, const float* __restrict__ W2,
                                               u16* __restrict__ W1T, u16* __restrict__ W2T) {
  const int b = blockIdx.x, t = threadIdx.x;
  if (b < KP) {
    W1T[(size_t)t * KP + b] = (b < F0) ? f2bf(W1[(size_t)b * D1 + t]) : (u16)0;
  } else {
    const int idx = (b - KP) * 256 + t;  // 0..8191
    const int k = idx & 255, n = idx >> 8;
    W2T[n * 256 + k] = f2bf(W2[k * 32 + n]);
  }
}

// ---------------- GEMM1: padA[MP][KP] @ W1T[256][KP]^T -> h1 bf16 [NN][256], epilogue * c_src ----------------
__global__ __launch_bounds__(256) void k_gemm1(const u16* __restrict__ A, const u16* __restrict__ BT,
                                               const float* __restrict__ csrc, u16* __restrict__ H) {
  __shared__ u16 As[128 * 32];
  __shared__ u16 Bs[128 * 32];
  const int tid = threadIdx.x;
  const int wave = tid >> 6, lane = tid & 63;
  const int l16 = lane & 15, quad = lane >> 4;
  const int waveM = wave & 1, waveN = wave >> 1;
  const int tn = blockIdx.x, tm = blockIdx.y;  // tn fastest: paired blocks share A-tile via L2/L3

  f32x4 acc[4][4];
#pragma unroll
  for (int mi = 0; mi < 4; ++mi)
#pragma unroll
    for (int ni = 0; ni < 4; ++ni) acc[mi][ni] = f32x4{0.f, 0.f, 0.f, 0.f};

  // staging: 512 16B chunks per tile; chunk c -> LDS byte offset 16*c; row c>>2, k-quad c&3
  const int c0 = wave * 64 + lane;
  const int rA0 = c0 >> 2, qA0 = (c0 & 3) * 8;
  const int rA1 = (c0 + 256) >> 2, qA1 = (c0 & 3) * 8;
  const u16* Ab = A + (size_t)tm * 128 * KP;
  const u16* Bb = BT + (size_t)tn * 128 * KP;
  u16* As0 = As + (wave * 64) * 8;           // wave-uniform LDS bases
  u16* As1 = As + (wave * 64 + 256) * 8;
  u16* Bs0 = Bs + (wave * 64) * 8;
  u16* Bs1 = Bs + (wave * 64 + 256) * 8;
  const size_t offA0 = (size_t)rA0 * KP + qA0;
  const size_t offA1 = (size_t)rA1 * KP + qA1;

  for (int kt = 0; kt < KP / 32; ++kt) {
    const int k0 = kt * 32;
    __syncthreads();
    gl16(Ab + offA0 + k0, As0);
    gl16(Ab + offA1 + k0, As1);
    gl16(Bb + offA0 + k0, Bs0);
    gl16(Bb + offA1 + k0, Bs1);
    __syncthreads();
    bf16x8 af[4], bfr[4];
#pragma unroll
    for (int mi = 0; mi < 4; ++mi)
      af[mi] = *(const bf16x8*)(As + ((waveM * 64 + mi * 16 + l16) * 32 + quad * 8));
#pragma unroll
    for (int ni = 0; ni < 4; ++ni)
      bfr[ni] = *(const bf16x8*)(Bs + ((waveN * 64 + ni * 16 + l16) * 32 + quad * 8));
#pragma unroll
    for (int mi = 0; mi < 4; ++mi)
#pragma unroll
      for (int ni = 0; ni < 4; ++ni)
        acc[mi][ni] = __builtin_amdgcn_mfma_f32_16x16x32_bf16(af[mi], bfr[ni], acc[mi][ni], 0, 0, 0);
  }

  // C/D: col = lane&15, row = quad*4 + reg  (verified m89/m91)
  const int rbase = tm * 128 + waveM * 64 + quad * 4;
  const int cbase = tn * 128 + waveN * 64 + l16;
#pragma unroll
  for (int mi = 0; mi < 4; ++mi) {
#pragma unroll
    for (int e = 0; e < 4; ++e) {
      const int i = rbase + mi * 16 + e;
      if (i < NN) {
        const float cs = csrc[i];
#pragma unroll
        for (int ni = 0; ni < 4; ++ni)
          H[(size_t)i * D1 + cbase + ni * 16] = f2bf(acc[mi][ni][e] * cs);
      }
    }
  }
}

// ---------------- SpMM1: agg[dst] += h1[src], one wave per edge ----------------
__global__ __launch_bounds__(256) void k_spmm1(const int* __restrict__ ei, const u16* __restrict__ h1,
                                               float* __restrict__ agg) {
  const int e = blockIdx.x * 4 + (threadIdx.x >> 6);
  const int lane = threadIdx.x & 63;
  const int s = ei[e];
  const int d = ei[NE + e];
  const u16* hs = h1 + (size_t)s * D1;
  float* ad = agg + (size_t)d * D1;
#pragma unroll
  for (int m = 0; m < 4; ++m) {
    const int f = m * 64 + lane;
    atomicAdd(&ad[f], bf2f(hs[f]));
  }
}

// x1s = relu(agg1*c_dst + b1) * c_src   (c_src folded for next GEMM)
__global__ __launch_bounds__(256) void k_post1(const float* __restrict__ agg, const float* __restrict__ cdst,
                                               const float* __restrict__ csrc, const float* __restrict__ b,
                                               u16* __restrict__ x) {
  const int i = blockIdx.x;
  const int j = threadIdx.x;
  const float v = agg[(size_t)i * D1 + j] * cdst[i] + b[j];
  x[(size_t)i * D1 + j] = f2bf(fmaxf(v, 0.f) * csrc[i]);
}

// ---------------- GEMM2: x1s[*][256] @ W2T[32][256]^T -> h2 bf16 [NN][32] ----------------
__global__ __launch_bounds__(256) void k_gemm2(const u16* __restrict__ A, const u16* __restrict__ BT,
                                               u16* __restrict__ H) {
  __shared__ u16 As[128 * 32];
  __shared__ u16 Bs[32 * 32];
  const int tid = threadIdx.x;
  const int wave = tid >> 6, lane = tid & 63;
  const int l16 = lane & 15, quad = lane >> 4;
  const int tm = blockIdx.x;

  f32x4 acc[2][2];
#pragma unroll
  for (int mi = 0; mi < 2; ++mi)
#pragma unroll
    for (int ni = 0; ni < 2; ++ni) acc[mi][ni] = f32x4{0.f, 0.f, 0.f, 0.f};

  const int r0 = tid >> 2, q0 = (tid & 3) * 8;
  for (int kt = 0; kt < 8; ++kt) {
    const int k0 = kt * 32;
    __syncthreads();
    uint4 v0 = *(const uint4*)(A + (size_t)(tm * 128 + r0) * D1 + k0 + q0);
    uint4 v1 = *(const uint4*)(A + (size_t)(tm * 128 + r0 + 64) * D1 + k0 + q0);
    *(uint4*)(As + r0 * 32 + q0) = v0;
    *(uint4*)(As + (r0 + 64) * 32 + q0) = v1;
    if (tid < 128) {
      uint4 vb = *(const uint4*)(BT + (size_t)r0 * D1 + k0 + q0);
      *(uint4*)(Bs + r0 * 32 + q0) = vb;
    }
    __syncthreads();
    bf16x8 af[2], bfr[2];
#pragma unroll
    for (int mi = 0; mi < 2; ++mi)
      af[mi] = *(const bf16x8*)(As + ((wave * 32 + mi * 16 + l16) * 32 + quad * 8));
#pragma unroll
    for (int ni = 0; ni < 2; ++ni)
      bfr[ni] = *(const bf16x8*)(Bs + ((ni * 16 + l16) * 32 + quad * 8));
#pragma unroll
    for (int mi = 0; mi < 2; ++mi)
#pragma unroll
      for (int ni = 0; ni < 2; ++ni)
        acc[mi][ni] = __builtin_amdgcn_mfma_f32_16x16x32_bf16(af[mi], bfr[ni], acc[mi][ni], 0, 0, 0);
  }

  const int rbase = tm * 128 + wave * 32 + quad * 4;
#pragma unroll
  for (int mi = 0; mi < 2; ++mi)
#pragma unroll
    for (int e = 0; e < 4; ++e) {
      const int i = rbase + mi * 16 + e;
      if (i < NN) {
#pragma unroll
        for (int ni = 0; ni < 2; ++ni)
          H[(size_t)i * D2 + ni * 16 + l16] = f2bf(acc[mi][ni][e]);
      }
    }
}

__global__ __launch_bounds__(256) void k_spmm2(const int* __restrict__ ei, const u16* __restrict__ h2,
                                               float* __restrict__ agg) {
  const int t = blockIdx.x * 256 + threadIdx.x;
  const int e = t >> 5, f = t & 31;
  const int s = ei[e], d = ei[NE + e];
  atomicAdd(&agg[(size_t)d * D2 + f], bf2f(h2[(size_t)s * D2 + f]));
}

__global__ __launch_bounds__(256) void k_post2(const float* __restrict__ agg, const float* __restrict__ cdst,
                                               const float* __restrict__ csrc, const float* __restrict__ b,
                                               u16* __restrict__ x) {
  const int t = blockIdx.x * 256 + threadIdx.x;
  const int i = t >> 5, j = t & 31;
  const float v = agg[t] * cdst[i] + b[j];
  x[t] = f2bf(fmaxf(v, 0.f) * csrc[i]);
}

// ---------------- layer3 matmul: h3[i][c] = sum_k x2s[i][k]*W3[k][c], f32 [NN][8] ----------------
__global__ __launch_bounds__(256) void k_l3(const u16* __restrict__ x, const float* __restrict__ W3,
                                            float* __restrict__ h3) {
  __shared__ float w3s[224];
  const int t = threadIdx.x;
  if (t < 224) w3s[t] = W3[t];
  __syncthreads();
  const int i = blockIdx.x * 256 + t;
  if (i >= NN) return;
  const uint4* p = (const uint4*)(x + (size_t)i * D2);
  union { uint4 v[4]; u16 s[32]; } u;
  u.v[0] = p[0]; u.v[1] = p[1]; u.v[2] = p[2]; u.v[3] = p[3];
  float acc[7];
#pragma unroll
  for (int c = 0; c < 7; ++c) acc[c] = 0.f;
#pragma unroll
  for (int k = 0; k < 32; ++k) {
    const float xv = bf2f(u.s[k]);
#pragma unroll
    for (int c = 0; c < 7; ++c) acc[c] += xv * w3s[k * 7 + c];
  }
  float* o = h3 + (size_t)i * 8;
#pragma unroll
  for (int c = 0; c < 7; ++c) o[c] = acc[c];
}

__global__ __launch_bounds__(256) void k_spmm3(const int* __restrict__ ei, const float* __restrict__ h3,
                                               float* __restrict__ agg) {
  const int t = blockIdx.x * 256 + threadIdx.x;
  const int e = t >> 3, c = t & 7;
  if (c < 7) {
    const int s = ei[e], d = ei[NE + e];
    atomicAdd(&agg[(size_t)d * 8 + c], h3[(size_t)s * 8 + c]);
  }
}

__global__ __launch_bounds__(256) void k_final(const float* __restrict__ agg, const float* __restrict__ cdst,
                                               const float* __restrict__ b3, float* __restrict__ out) {
  const int i = blockIdx.x * 256 + threadIdx.x;
  if (i >= NN) return;
  const float cd = cdst[i];
  float v[7];
  float m = -1e30f;
#pragma unroll
  for (int c = 0; c < 7; ++c) {
    v[c] = agg[(size_t)i * 8 + c] * cd + b3[c];
    m = fmaxf(m, v[c]);
  }
  float s = 0.f;
#pragma unroll
  for (int c = 0; c < 7; ++c) s += expf(v[c] - m);
  const float l = logf(s);
#pragma unroll
  for (int c = 0; c < 7; ++c) out[(size_t)i * 7 + c] = v[c] - m - l;
}

// ---------------- workspace layout (bytes) ----------------
static const size_t O_CSRC = 0;                      // f32 [NN]
static const size_t O_CDST = 200192;                 // f32 [NN]
static const size_t O_W1T  = 400384;                 // bf16 [256][KP]
static const size_t O_W2T  = 1137664;                // bf16 [32][256]
static const size_t O_H1   = 1154048;                // bf16 [NN][256]
static const size_t O_H2   = 26754048;               // bf16 [NN][32]
static const size_t O_B    = 29954048;               // big region, reused
static const size_t O_PADA = O_B;                    // bf16 [MP][KP] = 144.1 MB (GEMM1 only)
static const size_t O_AGG1 = O_B;                    // f32 [NN][256] (aliases padA, used after GEMM1)
static const size_t O_X1S  = O_B + 51200000;         // bf16 [NN][256]
static const size_t O_AGG2 = O_B + 76800000;         // f32 [NN][32]
static const size_t O_X2S  = O_B + 83200000;         // bf16 [NN][32]
static const size_t O_H3   = O_B + 86400000;         // f32 [NN][8]
static const size_t O_AGG3 = O_B + 88000000;         // f32 [NN][8]
// total ws needed: O_B + 144138240 = ~174.1 MB

extern "C" void kernel_launch(void* const* d_in, const int* in_sizes, int n_in,
                              void* d_out, int out_size, void* d_ws, size_t ws_size,
                              hipStream_t stream) {
  const float* feat = (const float*)d_in[0];
  const int* ei     = (const int*)d_in[1];
  const float* W1   = (const float*)d_in[2];
  const float* b1   = (const float*)d_in[3];
  const float* W2   = (const float*)d_in[4];
  const float* b2   = (const float*)d_in[5];
  const float* W3   = (const float*)d_in[6];
  const float* b3   = (const float*)d_in[7];
  float* out = (float*)d_out;

  char* ws = (char*)d_ws;
  float* c_src = (float*)(ws + O_CSRC);
  float* c_dst = (float*)(ws + O_CDST);
  u16* W1T  = (u16*)(ws + O_W1T);
  u16* W2T  = (u16*)(ws + O_W2T);
  u16* h1   = (u16*)(ws + O_H1);
  u16* h2   = (u16*)(ws + O_H2);
  u16* padA = (u16*)(ws + O_PADA);
  float* agg1 = (float*)(ws + O_AGG1);
  u16* x1s  = (u16*)(ws + O_X1S);
  float* agg2 = (float*)(ws + O_AGG2);
  u16* x2s  = (u16*)(ws + O_X2S);
  float* h3 = (float*)(ws + O_H3);
  float* agg3 = (float*)(ws + O_AGG3);

  // degrees -> rsqrt norms
  hipMemsetAsync(c_src, 0, (size_t)NN * 4, stream);
  hipMemsetAsync(c_dst, 0, (size_t)NN * 4, stream);
  k_deg<<<(NE + 255) / 256, 256, 0, stream>>>(ei, c_src, c_dst);
  k_rsqrt<<<(NN + 255) / 256, 256, 0, stream>>>(c_src, c_dst);

  // stage padded/converted A and transposed weights
  k_padA<<<dim3(3, MP), 256, 0, stream>>>(feat, padA);
  k_prepw<<<KP + 32, 256, 0, stream>>>(W1, W2, W1T, W2T);

  // layer 1
  k_gemm1<<<dim3(2, MP / 128), 256, 0, stream>>>(padA, W1T, c_src, h1);
  hipMemsetAsync(agg1, 0, (size_t)NN * D1 * 4, stream);   // after gemm1: aliases padA
  k_spmm1<<<NE / 4, 256, 0, stream>>>(ei, h1, agg1);
  k_post1<<<NN, 256, 0, stream>>>(agg1, c_dst, c_src, b1, x1s);

  // layer 2
  k_gemm2<<<MP / 128, 256, 0, stream>>>(x1s, W2T, h2);
  hipMemsetAsync(agg2, 0, (size_t)NN * D2 * 4, stream);
  k_spmm2<<<NE * 32 / 256, 256, 0, stream>>>(ei, h2, agg2);
  k_post2<<<NN * 32 / 256, 256, 0, stream>>>(agg2, c_dst, c_src, b2, x2s);

  // layer 3 + log_softmax
  k_l3<<<(NN + 255) / 256, 256, 0, stream>>>(x2s, W3, h3);
  hipMemsetAsync(agg3, 0, (size_t)NN * 8 * 4, stream);
  k_spmm3<<<NE * 8 / 256, 256, 0, stream>>>(ei, h3, agg3);
  k_final<<<(NN + 255) / 256, 256, 0, stream>>>(agg3, c_dst, b3, out);
}

// Round 3
// 1081.428 us; speedup vs baseline: 1.3133x; 1.3133x over previous
//
#include <hip/hip_runtime.h>
#include <math.h>

typedef unsigned short u16;
typedef unsigned int u32;
typedef __attribute__((ext_vector_type(8))) short bf16x8;   // 8 bf16 (4 VGPRs)
typedef __attribute__((ext_vector_type(4))) float f32x4;    // 4 fp32 acc

#define NN 50000    // nodes
#define NE 800000   // edges
#define F0 1433     // in feats
#define KP 1440     // padded K (45 * 32)
#define MP 50048    // padded M (391 * 128)
#define D1 256
#define D2 32
#define NB 196      // scan blocks: 196*256 = 50176 >= NN

__device__ __forceinline__ float bf2f(u16 h) { return __uint_as_float(((u32)h) << 16); }
__device__ __forceinline__ u16 f2bf(float f) {
  u32 u = __float_as_uint(f);
  u32 r = (u + 0x7FFFu + ((u >> 16) & 1u)) >> 16;  // RNE
  return (u16)r;
}

// async global->LDS, 16B per lane; LDS dest is wave-uniform base + lane*16
__device__ __forceinline__ void gl16(const void* g, void* l) {
  __builtin_amdgcn_global_load_lds((const __attribute__((address_space(1))) u32*)g,
                                   (__attribute__((address_space(3))) u32*)l, 16, 0, 0);
}

// ---------------- CSR build ----------------
__global__ __launch_bounds__(256) void k_hist(const int* __restrict__ ei,
                                              int* __restrict__ cs, int* __restrict__ cd) {
  const int e = blockIdx.x * 256 + threadIdx.x;
  if (e < NE) {
    atomicAdd(&cs[ei[e]], 1);
    atomicAdd(&cd[ei[NE + e]], 1);
  }
}

__global__ __launch_bounds__(256) void k_scan1(const int* __restrict__ cd, int* __restrict__ bsum) {
  __shared__ int sh[256];
  const int t = threadIdx.x;
  const int i = blockIdx.x * 256 + t;
  sh[t] = (i < NN) ? cd[i] : 0;
  __syncthreads();
  for (int o = 128; o > 0; o >>= 1) {
    if (t < o) sh[t] += sh[t + o];
    __syncthreads();
  }
  if (t == 0) bsum[blockIdx.x] = sh[0];
}

__global__ __launch_bounds__(256) void k_scan2(const int* __restrict__ bsum, int* __restrict__ boff) {
  __shared__ int sh[256];
  const int t = threadIdx.x;
  const int v = (t < NB) ? bsum[t] : 0;
  sh[t] = v;
  __syncthreads();
  for (int o = 1; o < 256; o <<= 1) {
    int x = (t >= o) ? sh[t - o] : 0;
    __syncthreads();
    sh[t] += x;
    __syncthreads();
  }
  if (t < NB) boff[t] = sh[t] - v;  // exclusive
}

// exclusive scan per block + base; emits row_start, cursor, and both norms
__global__ __launch_bounds__(256) void k_scan3(const int* __restrict__ cd, const int* __restrict__ cs,
                                               const int* __restrict__ boff,
                                               int* __restrict__ row, int* __restrict__ cur,
                                               float* __restrict__ cdst, float* __restrict__ csrc) {
  __shared__ int sh[256];
  const int t = threadIdx.x;
  const int i = blockIdx.x * 256 + t;
  const int v = (i < NN) ? cd[i] : 0;
  sh[t] = v;
  __syncthreads();
  for (int o = 1; o < 256; o <<= 1) {
    int x = (t >= o) ? sh[t - o] : 0;
    __syncthreads();
    sh[t] += x;
    __syncthreads();
  }
  if (i < NN) {
    const int start = boff[blockIdx.x] + sh[t] - v;
    row[i] = start;
    cur[i] = start;
    if (i == NN - 1) row[NN] = start + v;
    cdst[i] = rsqrtf(fmaxf((float)v, 1.0f));
    csrc[i] = rsqrtf(fmaxf((float)cs[i], 1.0f));
  }
}

__global__ __launch_bounds__(256) void k_scatter(const int* __restrict__ ei,
                                                 int* __restrict__ cur, int* __restrict__ csr) {
  const int e = blockIdx.x * 256 + threadIdx.x;
  if (e < NE) {
    const int d = ei[NE + e];
    const int p = atomicAdd(&cur[d], 1);
    csr[p] = ei[e];
  }
}

// ---------------- weights: W1 fp32[F0][256] -> bf16 W1T[256][KP]; W2 fp32[256][32] -> bf16 W2T[32][256] ----------------
__global__ __launch_bounds__(256) void k_prepw(const float* __restrict__ W1, const float* __restrict__ W2,
                                               u16* __restrict__ W1T, u16* __restrict__ W2T) {
  const int b = blockIdx.x, t = threadIdx.x;
  if (b < KP) {
    W1T[(size_t)t * KP + b] = (b < F0) ? f2bf(W1[(size_t)b * D1 + t]) : (u16)0;
  } else {
    const int idx = (b - KP) * 256 + t;  // 0..8191
    const int k = idx & 255, n = idx >> 8;
    W2T[n * 256 + k] = f2bf(W2[k * 32 + n]);
  }
}

// ---------------- GEMM1: feat fp32[NN][F0] (staged->bf16 in-kernel) @ W1T^T -> h1 bf16 [NN][256] * c_src ----------------
__global__ __launch_bounds__(256) void k_gemm1(const float* __restrict__ A, const u16* __restrict__ BT,
                                               const float* __restrict__ csrc, u16* __restrict__ H) {
  __shared__ u16 As[128 * 32];
  __shared__ u16 Bs[128 * 32];
  const int tid = threadIdx.x;
  const int wave = tid >> 6, lane = tid & 63;
  const int l16 = lane & 15, quad = lane >> 4;
  const int waveM = wave & 1, waveN = wave >> 1;
  const int tn = blockIdx.x, tm = blockIdx.y;  // tn fastest: paired blocks share A reads via L2/L3

  f32x4 acc[4][4];
#pragma unroll
  for (int mi = 0; mi < 4; ++mi)
#pragma unroll
    for (int ni = 0; ni < 4; ++ni) acc[mi][ni] = f32x4{0.f, 0.f, 0.f, 0.f};

  // A staging (fp32 -> bf16 via regs): thread covers chunks tid and tid+256.
  // chunk c: row c>>2 (0..127), k-offset (c&3)*8; LDS byte 16*c.
  const int cA0 = tid, cA1 = tid + 256;
  const int q0 = (cA0 & 3) * 8, q1 = (cA1 & 3) * 8;
  int row0 = tm * 128 + (cA0 >> 2); if (row0 >= NN) row0 = NN - 1;  // clamped rows: data staged but discarded
  int row1 = tm * 128 + (cA1 >> 2); if (row1 >= NN) row1 = NN - 1;
  const float* A0 = A + (size_t)row0 * F0 + q0;
  const float* A1 = A + (size_t)row1 * F0 + q1;

  // B staging via global_load_lds (bf16 already)
  const int c0 = wave * 64 + lane;
  const int rB0 = c0 >> 2, qB = (c0 & 3) * 8;
  const u16* Bb = BT + (size_t)tn * 128 * KP;
  u16* Bs0 = Bs + (wave * 64) * 8;          // wave-uniform LDS bases
  u16* Bs1 = Bs + (wave * 64 + 256) * 8;
  const size_t offB0 = (size_t)rB0 * KP + qB;
  const size_t offB1 = (size_t)(rB0 + 64) * KP + qB;

  for (int kt = 0; kt < KP / 32; ++kt) {
    const int k0 = kt * 32;
    // global fp32 loads (k-tail guarded), before barrier to overlap
    float f0[8], f1[8];
#pragma unroll
    for (int j = 0; j < 8; ++j) {
      f0[j] = (k0 + q0 + j < F0) ? A0[k0 + j] : 0.f;
      f1[j] = (k0 + q1 + j < F0) ? A1[k0 + j] : 0.f;
    }
    __syncthreads();  // prev iter's ds_reads done
    gl16(Bb + offB0 + k0, Bs0);
    gl16(Bb + offB1 + k0, Bs1);
    uint4 w0, w1;
    w0.x = (u32)f2bf(f0[0]) | ((u32)f2bf(f0[1]) << 16);
    w0.y = (u32)f2bf(f0[2]) | ((u32)f2bf(f0[3]) << 16);
    w0.z = (u32)f2bf(f0[4]) | ((u32)f2bf(f0[5]) << 16);
    w0.w = (u32)f2bf(f0[6]) | ((u32)f2bf(f0[7]) << 16);
    w1.x = (u32)f2bf(f1[0]) | ((u32)f2bf(f1[1]) << 16);
    w1.y = (u32)f2bf(f1[2]) | ((u32)f2bf(f1[3]) << 16);
    w1.z = (u32)f2bf(f1[4]) | ((u32)f2bf(f1[5]) << 16);
    w1.w = (u32)f2bf(f1[6]) | ((u32)f2bf(f1[7]) << 16);
    *(uint4*)(As + cA0 * 8) = w0;
    *(uint4*)(As + cA1 * 8) = w1;
    __syncthreads();  // LDS writes + gl16 visible
    bf16x8 af[4], bfr[4];
#pragma unroll
    for (int mi = 0; mi < 4; ++mi)
      af[mi] = *(const bf16x8*)(As + ((waveM * 64 + mi * 16 + l16) * 32 + quad * 8));
#pragma unroll
    for (int ni = 0; ni < 4; ++ni)
      bfr[ni] = *(const bf16x8*)(Bs + ((waveN * 64 + ni * 16 + l16) * 32 + quad * 8));
#pragma unroll
    for (int mi = 0; mi < 4; ++mi)
#pragma unroll
      for (int ni = 0; ni < 4; ++ni)
        acc[mi][ni] = __builtin_amdgcn_mfma_f32_16x16x32_bf16(af[mi], bfr[ni], acc[mi][ni], 0, 0, 0);
  }

  // C/D: col = lane&15, row = quad*4 + reg  (verified m89/m91)
  const int rbase = tm * 128 + waveM * 64 + quad * 4;
  const int cbase = tn * 128 + waveN * 64 + l16;
#pragma unroll
  for (int mi = 0; mi < 4; ++mi) {
#pragma unroll
    for (int e = 0; e < 4; ++e) {
      const int i = rbase + mi * 16 + e;
      if (i < NN) {
        const float cs = csrc[i];
#pragma unroll
        for (int ni = 0; ni < 4; ++ni)
          H[(size_t)i * D1 + cbase + ni * 16] = f2bf(acc[mi][ni][e] * cs);
      }
    }
  }
}

// ---------------- fused SpMM1+post1: x1s[d] = relu(sum_{s in N(d)} h1[s] * cdst[d] + b1) * csrc[d] ----------------
__global__ __launch_bounds__(256) void k_spmm1f(const int* __restrict__ row, const int* __restrict__ csr,
                                                const u16* __restrict__ h1, const float* __restrict__ cdst,
                                                const float* __restrict__ csrc, const float* __restrict__ b1,
                                                u16* __restrict__ x) {
  const int d = blockIdx.x * 4 + (threadIdx.x >> 6);   // grid exact: 12500*4 = NN
  const int lane = threadIdx.x & 63;
  const int rs = row[d], re = row[d + 1];
  float a0 = 0.f, a1 = 0.f, a2 = 0.f, a3 = 0.f;
  int e = rs;
  for (; e + 1 < re; e += 2) {   // unroll 2: two gathers in flight
    const int s0 = csr[e], s1 = csr[e + 1];
    const ushort4 v0 = *(const ushort4*)(h1 + (size_t)s0 * D1 + lane * 4);
    const ushort4 v1 = *(const ushort4*)(h1 + (size_t)s1 * D1 + lane * 4);
    a0 += bf2f(v0.x) + bf2f(v1.x);
    a1 += bf2f(v0.y) + bf2f(v1.y);
    a2 += bf2f(v0.z) + bf2f(v1.z);
    a3 += bf2f(v0.w) + bf2f(v1.w);
  }
  if (e < re) {
    const int s0 = csr[e];
    const ushort4 v0 = *(const ushort4*)(h1 + (size_t)s0 * D1 + lane * 4);
    a0 += bf2f(v0.x); a1 += bf2f(v0.y); a2 += bf2f(v0.z); a3 += bf2f(v0.w);
  }
  const float cd = cdst[d], cs = csrc[d];
  const float4 bb = *(const float4*)(b1 + lane * 4);
  const float r0 = fmaxf(a0 * cd + bb.x, 0.f) * cs;
  const float r1 = fmaxf(a1 * cd + bb.y, 0.f) * cs;
  const float r2 = fmaxf(a2 * cd + bb.z, 0.f) * cs;
  const float r3 = fmaxf(a3 * cd + bb.w, 0.f) * cs;
  ushort4 o;
  o.x = f2bf(r0); o.y = f2bf(r1); o.z = f2bf(r2); o.w = f2bf(r3);
  *(ushort4*)(x + (size_t)d * D1 + lane * 4) = o;
}

// ---------------- GEMM2: x1s[*][256] @ W2T[32][256]^T -> h2 bf16 [NN][32] ----------------
__global__ __launch_bounds__(256) void k_gemm2(const u16* __restrict__ A, const u16* __restrict__ BT,
                                               u16* __restrict__ H) {
  __shared__ u16 As[128 * 32];
  __shared__ u16 Bs[32 * 32];
  const int tid = threadIdx.x;
  const int wave = tid >> 6, lane = tid & 63;
  const int l16 = lane & 15, quad = lane >> 4;
  const int tm = blockIdx.x;

  f32x4 acc[2][2];
#pragma unroll
  for (int mi = 0; mi < 2; ++mi)
#pragma unroll
    for (int ni = 0; ni < 2; ++ni) acc[mi][ni] = f32x4{0.f, 0.f, 0.f, 0.f};

  const int r0 = tid >> 2, q0 = (tid & 3) * 8;
  int rowA0 = tm * 128 + r0;      if (rowA0 >= NN) rowA0 = NN - 1;
  int rowA1 = tm * 128 + r0 + 64; if (rowA1 >= NN) rowA1 = NN - 1;
  for (int kt = 0; kt < 8; ++kt) {
    const int k0 = kt * 32;
    __syncthreads();
    uint4 v0 = *(const uint4*)(A + (size_t)rowA0 * D1 + k0 + q0);
    uint4 v1 = *(const uint4*)(A + (size_t)rowA1 * D1 + k0 + q0);
    *(uint4*)(As + r0 * 32 + q0) = v0;
    *(uint4*)(As + (r0 + 64) * 32 + q0) = v1;
    if (tid < 128) {
      uint4 vb = *(const uint4*)(BT + (size_t)r0 * D1 + k0 + q0);
      *(uint4*)(Bs + r0 * 32 + q0) = vb;
    }
    __syncthreads();
    bf16x8 af[2], bfr[2];
#pragma unroll
    for (int mi = 0; mi < 2; ++mi)
      af[mi] = *(const bf16x8*)(As + ((wave * 32 + mi * 16 + l16) * 32 + quad * 8));
#pragma unroll
    for (int ni = 0; ni < 2; ++ni)
      bfr[ni] = *(const bf16x8*)(Bs + ((ni * 16 + l16) * 32 + quad * 8));
#pragma unroll
    for (int mi = 0; mi < 2; ++mi)
#pragma unroll
      for (int ni = 0; ni < 2; ++ni)
        acc[mi][ni] = __builtin_amdgcn_mfma_f32_16x16x32_bf16(af[mi], bfr[ni], acc[mi][ni], 0, 0, 0);
  }

  const int rbase = tm * 128 + wave * 32 + quad * 4;
#pragma unroll
  for (int mi = 0; mi < 2; ++mi)
#pragma unroll
    for (int e = 0; e < 4; ++e) {
      const int i = rbase + mi * 16 + e;
      if (i < NN) {
#pragma unroll
        for (int ni = 0; ni < 2; ++ni)
          H[(size_t)i * D2 + ni * 16 + l16] = f2bf(acc[mi][ni][e]);
      }
    }
}

// ---------------- fused SpMM2+post2 ----------------
__global__ __launch_bounds__(256) void k_spmm2f(const int* __restrict__ row, const int* __restrict__ csr,
                                                const u16* __restrict__ h2, const float* __restrict__ cdst,
                                                const float* __restrict__ csrc, const float* __restrict__ b2,
                                                u16* __restrict__ x) {
  const int t = threadIdx.x;
  const int d = blockIdx.x * 8 + (t >> 5);  // grid exact: 6250*8 = NN
  const int f = t & 31;
  const int rs = row[d], re = row[d + 1];
  float acc = 0.f;
  int e = rs;
  for (; e + 1 < re; e += 2) {
    const int s0 = csr[e], s1 = csr[e + 1];
    acc += bf2f(h2[(size_t)s0 * D2 + f]) + bf2f(h2[(size_t)s1 * D2 + f]);
  }
  if (e < re) acc += bf2f(h2[(size_t)csr[e] * D2 + f]);
  const float v = acc * cdst[d] + b2[f];
  x[(size_t)d * D2 + f] = f2bf(fmaxf(v, 0.f) * csrc[d]);
}

// ---------------- layer3 matmul: h3[i][c] = sum_k x2s[i][k]*W3[k][c], f32 [NN][8] ----------------
__global__ __launch_bounds__(256) void k_l3(const u16* __restrict__ x, const float* __restrict__ W3,
                                            float* __restrict__ h3) {
  __shared__ float w3s[224];
  const int t = threadIdx.x;
  if (t < 224) w3s[t] = W3[t];
  __syncthreads();
  const int i = blockIdx.x * 256 + t;
  if (i >= NN) return;
  const uint4* p = (const uint4*)(x + (size_t)i * D2);
  union { uint4 v[4]; u16 s[32]; } u;
  u.v[0] = p[0]; u.v[1] = p[1]; u.v[2] = p[2]; u.v[3] = p[3];
  float acc[7];
#pragma unroll
  for (int c = 0; c < 7; ++c) acc[c] = 0.f;
#pragma unroll
  for (int k = 0; k < 32; ++k) {
    const float xv = bf2f(u.s[k]);
#pragma unroll
    for (int c = 0; c < 7; ++c) acc[c] += xv * w3s[k * 7 + c];
  }
  float* o = h3 + (size_t)i * 8;
#pragma unroll
  for (int c = 0; c < 7; ++c) o[c] = acc[c];
}

// ---------------- fused SpMM3 + bias + log_softmax: 8 lanes per node ----------------
__global__ __launch_bounds__(256) void k_spmm3f(const int* __restrict__ row, const int* __restrict__ csr,
                                                const float* __restrict__ h3, const float* __restrict__ cdst,
                                                const float* __restrict__ b3, float* __restrict__ out) {
  const int t = threadIdx.x;
  const int d = blockIdx.x * 32 + (t >> 3);
  const int c = t & 7;
  if (d >= NN) return;
  const int rs = row[d], re = row[d + 1];
  float acc = 0.f;
  for (int e = rs; e < re; ++e) {
    const int s = csr[e];
    if (c < 7) acc += h3[(size_t)s * 8 + c];
  }
  const float v = (c < 7) ? (acc * cdst[d] + b3[c]) : -INFINITY;
  float m = v;
  m = fmaxf(m, __shfl_xor(m, 1));
  m = fmaxf(m, __shfl_xor(m, 2));
  m = fmaxf(m, __shfl_xor(m, 4));
  float s = (c < 7) ? expf(v - m) : 0.f;
  s += __shfl_xor(s, 1);
  s += __shfl_xor(s, 2);
  s += __shfl_xor(s, 4);
  const float l = logf(s);
  if (c < 7) out[(size_t)d * 7 + c] = v - m - l;
}

// ---------------- workspace layout (bytes), total ~64.4 MB ----------------
static const size_t O_CSRC = 0;           // f32 [NN]
static const size_t O_CDST = 200192;      // f32 [NN]
static const size_t O_ROW  = 400384;      // int [NN+1]
static const size_t O_CUR  = 600832;      // int [NN]
static const size_t O_CNTS = 801024;      // int [NN]
static const size_t O_CNTD = 1001216;     // int [NN]
static const size_t O_BSUM = 1201408;     // int [256]
static const size_t O_BOFF = 1202432;     // int [256]
static const size_t O_CSR  = 1203456;     // int [NE]
static const size_t O_W1T  = 4403456;     // bf16 [256][KP]
static const size_t O_W2T  = 5140736;     // bf16 [32][256]
static const size_t O_H1   = 5157120;     // bf16 [NN][256]
static const size_t O_X1S  = 30757120;    // bf16 [NN][256]
static const size_t O_H2   = 56357120;    // bf16 [NN][32]
static const size_t O_X2S  = 59557120;    // bf16 [NN][32]
static const size_t O_H3   = 62757120;    // f32 [NN][8]

extern "C" void kernel_launch(void* const* d_in, const int* in_sizes, int n_in,
                              void* d_out, int out_size, void* d_ws, size_t ws_size,
                              hipStream_t stream) {
  const float* feat = (const float*)d_in[0];
  const int* ei     = (const int*)d_in[1];
  const float* W1   = (const float*)d_in[2];
  const float* b1   = (const float*)d_in[3];
  const float* W2   = (const float*)d_in[4];
  const float* b2   = (const float*)d_in[5];
  const float* W3   = (const float*)d_in[6];
  const float* b3   = (const float*)d_in[7];
  float* out = (float*)d_out;

  char* ws = (char*)d_ws;
  float* c_src = (float*)(ws + O_CSRC);
  float* c_dst = (float*)(ws + O_CDST);
  int* row  = (int*)(ws + O_ROW);
  int* cur  = (int*)(ws + O_CUR);
  int* cnts = (int*)(ws + O_CNTS);
  int* cntd = (int*)(ws + O_CNTD);
  int* bsum = (int*)(ws + O_BSUM);
  int* boff = (int*)(ws + O_BOFF);
  int* csr  = (int*)(ws + O_CSR);
  u16* W1T  = (u16*)(ws + O_W1T);
  u16* W2T  = (u16*)(ws + O_W2T);
  u16* h1   = (u16*)(ws + O_H1);
  u16* x1s  = (u16*)(ws + O_X1S);
  u16* h2   = (u16*)(ws + O_H2);
  u16* x2s  = (u16*)(ws + O_X2S);
  float* h3 = (float*)(ws + O_H3);

  // CSR build + norms
  hipMemsetAsync(cnts, 0, (size_t)NN * 4, stream);
  hipMemsetAsync(cntd, 0, (size_t)NN * 4, stream);
  k_hist<<<(NE + 255) / 256, 256, 0, stream>>>(ei, cnts, cntd);
  k_scan1<<<NB, 256, 0, stream>>>(cntd, bsum);
  k_scan2<<<1, 256, 0, stream>>>(bsum, boff);
  k_scan3<<<NB, 256, 0, stream>>>(cntd, cnts, boff, row, cur, c_dst, c_src);
  k_scatter<<<(NE + 255) / 256, 256, 0, stream>>>(ei, cur, csr);

  // weights
  k_prepw<<<KP + 32, 256, 0, stream>>>(W1, W2, W1T, W2T);

  // layer 1
  k_gemm1<<<dim3(2, MP / 128), 256, 0, stream>>>(feat, W1T, c_src, h1);
  k_spmm1f<<<NN / 4, 256, 0, stream>>>(row, csr, h1, c_dst, c_src, b1, x1s);

  // layer 2
  k_gemm2<<<MP / 128, 256, 0, stream>>>(x1s, W2T, h2);
  k_spmm2f<<<NN / 8, 256, 0, stream>>>(row, csr, h2, c_dst, c_src, b2, x2s);

  // layer 3 + log_softmax
  k_l3<<<(NN + 255) / 256, 256, 0, stream>>>(x2s, W3, h3);
  k_spmm3f<<<(NN + 31) / 32, 256, 0, stream>>>(row, csr, h3, c_dst, b3, out);
}

// Round 4
// 777.754 us; speedup vs baseline: 1.8261x; 1.3905x over previous
//
#include <hip/hip_runtime.h>
#include <math.h>

typedef unsigned short u16;
typedef unsigned int u32;
typedef __attribute__((ext_vector_type(8))) short bf16x8;   // 8 bf16 (4 VGPRs)
typedef __attribute__((ext_vector_type(4))) float f32x4;    // 4 fp32 acc

#define NN 50000    // nodes
#define NE 800000   // edges
#define F0 1433     // in feats
#define KP 1440     // padded K (45 * 32)
#define MP 50048    // padded M (391 * 128)
#define D1 256
#define D2 32
#define NB 196      // scan blocks: 196*256 = 50176 >= NN

__device__ __forceinline__ float bf2f(u16 h) { return __uint_as_float(((u32)h) << 16); }
__device__ __forceinline__ u16 f2bf(float f) {
  u32 u = __float_as_uint(f);
  u32 r = (u + 0x7FFFu + ((u >> 16) & 1u)) >> 16;  // RNE
  return (u16)r;
}

// async global->LDS, 16B per lane; LDS dest is wave-uniform base + lane*16
__device__ __forceinline__ void gl16(const void* g, void* l) {
  __builtin_amdgcn_global_load_lds((const __attribute__((address_space(1))) u32*)g,
                                   (__attribute__((address_space(3))) u32*)l, 16, 0, 0);
}

// ---------------- CSR build ----------------
__global__ __launch_bounds__(256) void k_hist(const int* __restrict__ ei,
                                              int* __restrict__ cs, int* __restrict__ cd) {
  const int e = blockIdx.x * 256 + threadIdx.x;
  if (e < NE) {
    atomicAdd(&cs[ei[e]], 1);
    atomicAdd(&cd[ei[NE + e]], 1);
  }
}

__global__ __launch_bounds__(256) void k_scan1(const int* __restrict__ cd, int* __restrict__ bsum) {
  __shared__ int sh[256];
  const int t = threadIdx.x;
  const int i = blockIdx.x * 256 + t;
  sh[t] = (i < NN) ? cd[i] : 0;
  __syncthreads();
  for (int o = 128; o > 0; o >>= 1) {
    if (t < o) sh[t] += sh[t + o];
    __syncthreads();
  }
  if (t == 0) bsum[blockIdx.x] = sh[0];
}

__global__ __launch_bounds__(256) void k_scan2(const int* __restrict__ bsum, int* __restrict__ boff) {
  __shared__ int sh[256];
  const int t = threadIdx.x;
  const int v = (t < NB) ? bsum[t] : 0;
  sh[t] = v;
  __syncthreads();
  for (int o = 1; o < 256; o <<= 1) {
    int x = (t >= o) ? sh[t - o] : 0;
    __syncthreads();
    sh[t] += x;
    __syncthreads();
  }
  if (t < NB) boff[t] = sh[t] - v;  // exclusive
}

// exclusive scan per block + base; emits row_start, cursor, and both norms
__global__ __launch_bounds__(256) void k_scan3(const int* __restrict__ cd, const int* __restrict__ cs,
                                               const int* __restrict__ boff,
                                               int* __restrict__ row, int* __restrict__ cur,
                                               float* __restrict__ cdst, float* __restrict__ csrc) {
  __shared__ int sh[256];
  const int t = threadIdx.x;
  const int i = blockIdx.x * 256 + t;
  const int v = (i < NN) ? cd[i] : 0;
  sh[t] = v;
  __syncthreads();
  for (int o = 1; o < 256; o <<= 1) {
    int x = (t >= o) ? sh[t - o] : 0;
    __syncthreads();
    sh[t] += x;
    __syncthreads();
  }
  if (i < NN) {
    const int start = boff[blockIdx.x] + sh[t] - v;
    row[i] = start;
    cur[i] = start;
    if (i == NN - 1) row[NN] = start + v;
    cdst[i] = rsqrtf(fmaxf((float)v, 1.0f));
    csrc[i] = rsqrtf(fmaxf((float)cs[i], 1.0f));
  }
}

__global__ __launch_bounds__(256) void k_scatter(const int* __restrict__ ei,
                                                 int* __restrict__ cur, int* __restrict__ csr) {
  const int e = blockIdx.x * 256 + threadIdx.x;
  if (e < NE) {
    const int d = ei[NE + e];
    const int p = atomicAdd(&cur[d], 1);
    csr[p] = ei[e];
  }
}

// ---------------- pad+convert features fp32 [NN][F0] -> bf16 [MP][KP] ----------------
__global__ __launch_bounds__(256) void k_padA(const float* __restrict__ F, u16* __restrict__ P) {
  const int t = blockIdx.x * 256 + threadIdx.x;  // 0..767, need 720
  if (t >= 720) return;
  const int i = blockIdx.y;
  const int k = t * 2;
  u32 v = 0;
  if (i < NN) {
    const size_t base = (size_t)i * F0;
    u32 lo = (k < F0) ? (u32)f2bf(F[base + k]) : 0u;
    u32 hi = (k + 1 < F0) ? (u32)f2bf(F[base + k + 1]) : 0u;
    v = lo | (hi << 16);
  }
  *(u32*)(P + (size_t)i * KP + k) = v;  // dst 4B-aligned (KP even)
}

// ---------------- weights: W1 fp32[F0][256] -> bf16 W1T[256][KP]; W2 fp32[256][32] -> bf16 W2T[32][256] ----------------
__global__ __launch_bounds__(256) void k_prepw(const float* __restrict__ W1, const float* __restrict__ W2,
                                               u16* __restrict__ W1T, u16* __restrict__ W2T) {
  const int b = blockIdx.x, t = threadIdx.x;
  if (b < KP) {
    W1T[(size_t)t * KP + b] = (b < F0) ? f2bf(W1[(size_t)b * D1 + t]) : (u16)0;
  } else {
    const int idx = (b - KP) * 256 + t;  // 0..8191
    const int k = idx & 255, n = idx >> 8;
    W2T[n * 256 + k] = f2bf(W2[k * 32 + n]);
  }
}

// ---------------- GEMM1: padA[MP][KP] @ W1T[256][KP]^T -> h1 bf16 [NN][256], epilogue * c_src ----------------
__global__ __launch_bounds__(256) void k_gemm1(const u16* __restrict__ A, const u16* __restrict__ BT,
                                               const float* __restrict__ csrc, u16* __restrict__ H) {
  __shared__ u16 As[128 * 32];
  __shared__ u16 Bs[128 * 32];
  const int tid = threadIdx.x;
  const int wave = tid >> 6, lane = tid & 63;
  const int l16 = lane & 15, quad = lane >> 4;
  const int waveM = wave & 1, waveN = wave >> 1;
  const int tn = blockIdx.x, tm = blockIdx.y;  // tn fastest: paired blocks share A-tile via L2

  f32x4 acc[4][4];
#pragma unroll
  for (int mi = 0; mi < 4; ++mi)
#pragma unroll
    for (int ni = 0; ni < 4; ++ni) acc[mi][ni] = f32x4{0.f, 0.f, 0.f, 0.f};

  // staging: 512 16B chunks per tile; chunk c -> LDS byte 16*c; row c>>2, k-quad c&3
  const int c0 = wave * 64 + lane;
  const int rA0 = c0 >> 2, qA0 = (c0 & 3) * 8;
  const u16* Ab = A + (size_t)tm * 128 * KP;
  const u16* Bb = BT + (size_t)tn * 128 * KP;
  u16* As0 = As + (wave * 64) * 8;           // wave-uniform LDS bases
  u16* As1 = As + (wave * 64 + 256) * 8;
  u16* Bs0 = Bs + (wave * 64) * 8;
  u16* Bs1 = Bs + (wave * 64 + 256) * 8;
  const size_t off0 = (size_t)rA0 * KP + qA0;
  const size_t off1 = (size_t)(rA0 + 64) * KP + qA0;

  for (int kt = 0; kt < KP / 32; ++kt) {
    const int k0 = kt * 32;
    __syncthreads();
    gl16(Ab + off0 + k0, As0);
    gl16(Ab + off1 + k0, As1);
    gl16(Bb + off0 + k0, Bs0);
    gl16(Bb + off1 + k0, Bs1);
    __syncthreads();
    bf16x8 af[4], bfr[4];
#pragma unroll
    for (int mi = 0; mi < 4; ++mi)
      af[mi] = *(const bf16x8*)(As + ((waveM * 64 + mi * 16 + l16) * 32 + quad * 8));
#pragma unroll
    for (int ni = 0; ni < 4; ++ni)
      bfr[ni] = *(const bf16x8*)(Bs + ((waveN * 64 + ni * 16 + l16) * 32 + quad * 8));
#pragma unroll
    for (int mi = 0; mi < 4; ++mi)
#pragma unroll
      for (int ni = 0; ni < 4; ++ni)
        acc[mi][ni] = __builtin_amdgcn_mfma_f32_16x16x32_bf16(af[mi], bfr[ni], acc[mi][ni], 0, 0, 0);
  }

  // C/D: col = lane&15, row = quad*4 + reg  (verified m89/m91)
  const int rbase = tm * 128 + waveM * 64 + quad * 4;
  const int cbase = tn * 128 + waveN * 64 + l16;
#pragma unroll
  for (int mi = 0; mi < 4; ++mi) {
#pragma unroll
    for (int e = 0; e < 4; ++e) {
      const int i = rbase + mi * 16 + e;
      if (i < NN) {
        const float cs = csrc[i];
#pragma unroll
        for (int ni = 0; ni < 4; ++ni)
          H[(size_t)i * D1 + cbase + ni * 16] = f2bf(acc[mi][ni][e] * cs);
      }
    }
  }
}

// ---------------- fused SpMM1+post1: x1s[d] = relu(sum_{s in N(d)} h1[s] * cdst[d] + b1) * csrc[d] ----------------
__global__ __launch_bounds__(256) void k_spmm1f(const int* __restrict__ row, const int* __restrict__ csr,
                                                const u16* __restrict__ h1, const float* __restrict__ cdst,
                                                const float* __restrict__ csrc, const float* __restrict__ b1,
                                                u16* __restrict__ x) {
  const int d = blockIdx.x * 4 + (threadIdx.x >> 6);   // grid exact: 12500*4 = NN
  const int lane = threadIdx.x & 63;
  const int rs = row[d], re = row[d + 1];
  float a0 = 0.f, a1 = 0.f, a2 = 0.f, a3 = 0.f;
  int e = rs;
  for (; e + 1 < re; e += 2) {   // unroll 2: two gathers in flight
    const int s0 = csr[e], s1 = csr[e + 1];
    const ushort4 v0 = *(const ushort4*)(h1 + (size_t)s0 * D1 + lane * 4);
    const ushort4 v1 = *(const ushort4*)(h1 + (size_t)s1 * D1 + lane * 4);
    a0 += bf2f(v0.x) + bf2f(v1.x);
    a1 += bf2f(v0.y) + bf2f(v1.y);
    a2 += bf2f(v0.z) + bf2f(v1.z);
    a3 += bf2f(v0.w) + bf2f(v1.w);
  }
  if (e < re) {
    const int s0 = csr[e];
    const ushort4 v0 = *(const ushort4*)(h1 + (size_t)s0 * D1 + lane * 4);
    a0 += bf2f(v0.x); a1 += bf2f(v0.y); a2 += bf2f(v0.z); a3 += bf2f(v0.w);
  }
  const float cd = cdst[d], cs = csrc[d];
  const float4 bb = *(const float4*)(b1 + lane * 4);
  const float r0 = fmaxf(a0 * cd + bb.x, 0.f) * cs;
  const float r1 = fmaxf(a1 * cd + bb.y, 0.f) * cs;
  const float r2 = fmaxf(a2 * cd + bb.z, 0.f) * cs;
  const float r3 = fmaxf(a3 * cd + bb.w, 0.f) * cs;
  ushort4 o;
  o.x = f2bf(r0); o.y = f2bf(r1); o.z = f2bf(r2); o.w = f2bf(r3);
  *(ushort4*)(x + (size_t)d * D1 + lane * 4) = o;
}

// ---------------- GEMM2: x1s[*][256] @ W2T[32][256]^T -> h2 bf16 [NN][32] ----------------
__global__ __launch_bounds__(256) void k_gemm2(const u16* __restrict__ A, const u16* __restrict__ BT,
                                               u16* __restrict__ H) {
  __shared__ u16 As[128 * 32];
  __shared__ u16 Bs[32 * 32];
  const int tid = threadIdx.x;
  const int wave = tid >> 6, lane = tid & 63;
  const int l16 = lane & 15, quad = lane >> 4;
  const int tm = blockIdx.x;

  f32x4 acc[2][2];
#pragma unroll
  for (int mi = 0; mi < 2; ++mi)
#pragma unroll
    for (int ni = 0; ni < 2; ++ni) acc[mi][ni] = f32x4{0.f, 0.f, 0.f, 0.f};

  const int r0 = tid >> 2, q0 = (tid & 3) * 8;
  int rowA0 = tm * 128 + r0;      if (rowA0 >= NN) rowA0 = NN - 1;
  int rowA1 = tm * 128 + r0 + 64; if (rowA1 >= NN) rowA1 = NN - 1;
  for (int kt = 0; kt < 8; ++kt) {
    const int k0 = kt * 32;
    __syncthreads();
    uint4 v0 = *(const uint4*)(A + (size_t)rowA0 * D1 + k0 + q0);
    uint4 v1 = *(const uint4*)(A + (size_t)rowA1 * D1 + k0 + q0);
    *(uint4*)(As + r0 * 32 + q0) = v0;
    *(uint4*)(As + (r0 + 64) * 32 + q0) = v1;
    if (tid < 128) {
      uint4 vb = *(const uint4*)(BT + (size_t)r0 * D1 + k0 + q0);
      *(uint4*)(Bs + r0 * 32 + q0) = vb;
    }
    __syncthreads();
    bf16x8 af[2], bfr[2];
#pragma unroll
    for (int mi = 0; mi < 2; ++mi)
      af[mi] = *(const bf16x8*)(As + ((wave * 32 + mi * 16 + l16) * 32 + quad * 8));
#pragma unroll
    for (int ni = 0; ni < 2; ++ni)
      bfr[ni] = *(const bf16x8*)(Bs + ((ni * 16 + l16) * 32 + quad * 8));
#pragma unroll
    for (int mi = 0; mi < 2; ++mi)
#pragma unroll
      for (int ni = 0; ni < 2; ++ni)
        acc[mi][ni] = __builtin_amdgcn_mfma_f32_16x16x32_bf16(af[mi], bfr[ni], acc[mi][ni], 0, 0, 0);
  }

  const int rbase = tm * 128 + wave * 32 + quad * 4;
#pragma unroll
  for (int mi = 0; mi < 2; ++mi)
#pragma unroll
    for (int e = 0; e < 4; ++e) {
      const int i = rbase + mi * 16 + e;
      if (i < NN) {
#pragma unroll
        for (int ni = 0; ni < 2; ++ni)
          H[(size_t)i * D2 + ni * 16 + l16] = f2bf(acc[mi][ni][e]);
      }
    }
}

// ---------------- fused SpMM2+post2 ----------------
__global__ __launch_bounds__(256) void k_spmm2f(const int* __restrict__ row, const int* __restrict__ csr,
                                                const u16* __restrict__ h2, const float* __restrict__ cdst,
                                                const float* __restrict__ csrc, const float* __restrict__ b2,
                                                u16* __restrict__ x) {
  const int t = threadIdx.x;
  const int d = blockIdx.x * 8 + (t >> 5);  // grid exact: 6250*8 = NN
  const int f = t & 31;
  const int rs = row[d], re = row[d + 1];
  float acc = 0.f;
  int e = rs;
  for (; e + 1 < re; e += 2) {
    const int s0 = csr[e], s1 = csr[e + 1];
    acc += bf2f(h2[(size_t)s0 * D2 + f]) + bf2f(h2[(size_t)s1 * D2 + f]);
  }
  if (e < re) acc += bf2f(h2[(size_t)csr[e] * D2 + f]);
  const float v = acc * cdst[d] + b2[f];
  x[(size_t)d * D2 + f] = f2bf(fmaxf(v, 0.f) * csrc[d]);
}

// ---------------- layer3 matmul: h3[i][c] = sum_k x2s[i][k]*W3[k][c], f32 [NN][8] ----------------
__global__ __launch_bounds__(256) void k_l3(const u16* __restrict__ x, const float* __restrict__ W3,
                                            float* __restrict__ h3) {
  __shared__ float w3s[224];
  const int t = threadIdx.x;
  if (t < 224) w3s[t] = W3[t];
  __syncthreads();
  const int i = blockIdx.x * 256 + t;
  if (i >= NN) return;
  const uint4* p = (const uint4*)(x + (size_t)i * D2);
  union { uint4 v[4]; u16 s[32]; } u;
  u.v[0] = p[0]; u.v[1] = p[1]; u.v[2] = p[2]; u.v[3] = p[3];
  float acc[7];
#pragma unroll
  for (int c = 0; c < 7; ++c) acc[c] = 0.f;
#pragma unroll
  for (int k = 0; k < 32; ++k) {
    const float xv = bf2f(u.s[k]);
#pragma unroll
    for (int c = 0; c < 7; ++c) acc[c] += xv * w3s[k * 7 + c];
  }
  float* o = h3 + (size_t)i * 8;
#pragma unroll
  for (int c = 0; c < 7; ++c) o[c] = acc[c];
}

// ---------------- fused SpMM3 + bias + log_softmax: 8 lanes per node ----------------
__global__ __launch_bounds__(256) void k_spmm3f(const int* __restrict__ row, const int* __restrict__ csr,
                                                const float* __restrict__ h3, const float* __restrict__ cdst,
                                                const float* __restrict__ b3, float* __restrict__ out) {
  const int t = threadIdx.x;
  const int d = blockIdx.x * 32 + (t >> 3);
  const int c = t & 7;
  if (d >= NN) return;
  const int rs = row[d], re = row[d + 1];
  float acc = 0.f;
  for (int e = rs; e < re; ++e) {
    const int s = csr[e];
    if (c < 7) acc += h3[(size_t)s * 8 + c];
  }
  const float v = (c < 7) ? (acc * cdst[d] + b3[c]) : -INFINITY;
  float m = v;
  m = fmaxf(m, __shfl_xor(m, 1));
  m = fmaxf(m, __shfl_xor(m, 2));
  m = fmaxf(m, __shfl_xor(m, 4));
  float s = (c < 7) ? expf(v - m) : 0.f;
  s += __shfl_xor(s, 1);
  s += __shfl_xor(s, 2);
  s += __shfl_xor(s, 4);
  const float l = logf(s);
  if (c < 7) out[(size_t)d * 7 + c] = v - m - l;
}

// ---------------- workspace layout (bytes) ----------------
static const size_t O_CSRC = 0;           // f32 [NN]
static const size_t O_CDST = 200192;      // f32 [NN]
static const size_t O_ROW  = 400384;      // int [NN+1]
static const size_t O_CUR  = 601088;      // int [NN]
static const size_t O_CNTS = 801792;      // int [NN]
static const size_t O_CNTD = 1002496;     // int [NN]
static const size_t O_BSUM = 1203200;     // int [256]
static const size_t O_BOFF = 1204224;     // int [256]
static const size_t O_CSR  = 1205248;     // int [NE]
static const size_t O_W1T  = 4405248;     // bf16 [256][KP]
static const size_t O_W2T  = 5142528;     // bf16 [32][256]
static const size_t O_H1   = 5158912;     // bf16 [NN][256]
static const size_t O_PADA = 30758912;    // bf16 [MP][KP] = 144.1 MB (dead after gemm1)
static const size_t O_X1S  = O_PADA;                // bf16 [NN][256] (aliases padA)
static const size_t O_H2   = O_PADA + 25600000;     // bf16 [NN][32]
static const size_t O_X2S  = O_PADA + 28800000;     // bf16 [NN][32]
static const size_t O_H3   = O_PADA + 32000000;     // f32 [NN][8]
// total ws needed: 30758912 + 144138240 = ~174.9 MB (same envelope as round 1/2)

extern "C" void kernel_launch(void* const* d_in, const int* in_sizes, int n_in,
                              void* d_out, int out_size, void* d_ws, size_t ws_size,
                              hipStream_t stream) {
  const float* feat = (const float*)d_in[0];
  const int* ei     = (const int*)d_in[1];
  const float* W1   = (const float*)d_in[2];
  const float* b1   = (const float*)d_in[3];
  const float* W2   = (const float*)d_in[4];
  const float* b2   = (const float*)d_in[5];
  const float* W3   = (const float*)d_in[6];
  const float* b3   = (const float*)d_in[7];
  float* out = (float*)d_out;

  char* ws = (char*)d_ws;
  float* c_src = (float*)(ws + O_CSRC);
  float* c_dst = (float*)(ws + O_CDST);
  int* row  = (int*)(ws + O_ROW);
  int* cur  = (int*)(ws + O_CUR);
  int* cnts = (int*)(ws + O_CNTS);
  int* cntd = (int*)(ws + O_CNTD);
  int* bsum = (int*)(ws + O_BSUM);
  int* boff = (int*)(ws + O_BOFF);
  int* csr  = (int*)(ws + O_CSR);
  u16* W1T  = (u16*)(ws + O_W1T);
  u16* W2T  = (u16*)(ws + O_W2T);
  u16* h1   = (u16*)(ws + O_H1);
  u16* padA = (u16*)(ws + O_PADA);
  u16* x1s  = (u16*)(ws + O_X1S);
  u16* h2   = (u16*)(ws + O_H2);
  u16* x2s  = (u16*)(ws + O_X2S);
  float* h3 = (float*)(ws + O_H3);

  // CSR build + norms
  hipMemsetAsync(cnts, 0, (size_t)NN * 4, stream);
  hipMemsetAsync(cntd, 0, (size_t)NN * 4, stream);
  k_hist<<<(NE + 255) / 256, 256, 0, stream>>>(ei, cnts, cntd);
  k_scan1<<<NB, 256, 0, stream>>>(cntd, bsum);
  k_scan2<<<1, 256, 0, stream>>>(bsum, boff);
  k_scan3<<<NB, 256, 0, stream>>>(cntd, cnts, boff, row, cur, c_dst, c_src);
  k_scatter<<<(NE + 255) / 256, 256, 0, stream>>>(ei, cur, csr);

  // staging: padded bf16 features + transposed weights
  k_padA<<<dim3(3, MP), 256, 0, stream>>>(feat, padA);
  k_prepw<<<KP + 32, 256, 0, stream>>>(W1, W2, W1T, W2T);

  // layer 1
  k_gemm1<<<dim3(2, MP / 128), 256, 0, stream>>>(padA, W1T, c_src, h1);
  k_spmm1f<<<NN / 4, 256, 0, stream>>>(row, csr, h1, c_dst, c_src, b1, x1s);

  // layer 2
  k_gemm2<<<MP / 128, 256, 0, stream>>>(x1s, W2T, h2);
  k_spmm2f<<<NN / 8, 256, 0, stream>>>(row, csr, h2, c_dst, c_src, b2, x2s);

  // layer 3 + log_softmax
  k_l3<<<(NN + 255) / 256, 256, 0, stream>>>(x2s, W3, h3);
  k_spmm3f<<<(NN + 31) / 32, 256, 0, stream>>>(row, csr, h3, c_dst, b3, out);
}